// Round 14
// baseline (253.590 us; speedup 1.0000x reference)
//
#include <hip/hip_runtime.h>
#include <stdint.h>

// ---------------------------------------------------------------------------
// MultiHeadAttention: B=1, S=4096, H=1024, NH=16, DH=64
//   q = relu(Q @ Wq^T + bq), k = ..., v = ...
//   per head: softmax(q k^T / 8) v,   output scrambled (torch-faithful
//   transpose(0,1,3,2).reshape) + queries.
// R14: R13 + row-sum tw-combine fix (R13 bug: tw=0/tw=1 waves raced on the
//      same rsb slot -> denominator halved -> absmax 0.31). Row-sums now
//      combined across tw in LDS before one global write. attn KV-split:
//      2 blocks per (head, 256q) x 2048 t each; wave = 64 q x 32 t.
//      prep_w / qkv_gemm / attn_norm = R13.
// ---------------------------------------------------------------------------

#define SEQ 4096
#define HID 1024
#define NHEAD 16
#define DHEAD 64

typedef __attribute__((ext_vector_type(8))) short short8_t;     // 8 x bf16
typedef __attribute__((ext_vector_type(4))) float f32x4;        // 16x16 acc
typedef __attribute__((ext_vector_type(16))) float f32x16;      // 32x32 acc
typedef __attribute__((ext_vector_type(2))) unsigned int u32x2;

// ws layout (bf16 elements)
// [0 .. 8388608)            opart bf16 [2][16][64][4096]  (attn partials)
// [8388608 .. 8650752)      rs f32 [2][16][4096] (viewed as f32)
#define WS_WQ   12582912u   // weights bf16 [1024][1024] x3
#define WS_QO   15728640u   // q proj [4096][1024]
#define WS_KO   19922944u   // k proj (pre-scaled by (1/8)*log2e) [4096][1024]
#define WS_VT   24117248u   // v proj transposed [16][64][4096]

__device__ __forceinline__ unsigned short f2bf(float f) {
  union { float f; unsigned int u; } x; x.f = f;
  unsigned int u = x.u;
  return (unsigned short)((u + 0x7FFFu + ((u >> 16) & 1u)) >> 16);
}

__device__ __forceinline__ float b2f(unsigned short h) {
  union { unsigned int u; float f; } x;
  x.u = (unsigned int)h << 16;
  return x.f;
}

// raw v_exp_f32 — valid: inputs are >= 0 (ReLU'd Q,K dot) and < ~16
__device__ __forceinline__ float fexp2(float x) {
#if __has_builtin(__builtin_amdgcn_exp2f)
  return __builtin_amdgcn_exp2f(x);
#else
  float r; asm("v_exp_f32 %0, %1" : "=v"(r) : "v"(x)); return r;
#endif
}

// packed f32x2 -> bf16x2 (lo = a, hi = b)
__device__ __forceinline__ unsigned int pk2(float a, float b) {
  unsigned int r;
  asm("v_cvt_pk_bf16_f32 %0, %1, %2" : "=v"(r) : "v"(a), "v"(b));
  return r;
}

// swap hi-32-lanes of a with lo-32-lanes of b
__device__ __forceinline__ void pl32swap(unsigned int& a, unsigned int& b) {
  asm("v_permlane32_swap_b32 %0, %1" : "+v"(a), "+v"(b));
}

__device__ __forceinline__ void gll16(const void* g, void* l) {
  __builtin_amdgcn_global_load_lds(
      (const __attribute__((address_space(1))) void*)g,
      (__attribute__((address_space(3))) void*)l, 16, 0, 0);
}

// P pack+redistribute: acs (S^T regs=t, lane=s col) -> two PV A-frags
__device__ __forceinline__ void packP(const f32x16& a, short8_t& p0,
                                      short8_t& p1) {
  unsigned int w0 = pk2(a[0], a[1]),   w1 = pk2(a[2], a[3]);
  unsigned int w2 = pk2(a[4], a[5]),   w3 = pk2(a[6], a[7]);
  unsigned int w4 = pk2(a[8], a[9]),   w5 = pk2(a[10], a[11]);
  unsigned int w6 = pk2(a[12], a[13]), w7 = pk2(a[14], a[15]);
  pl32swap(w0, w2);
  pl32swap(w1, w3);
  pl32swap(w4, w6);
  pl32swap(w5, w7);
  union { unsigned int u[4]; short8_t v; } q0, q1;
  q0.u[0] = w0; q0.u[1] = w1; q0.u[2] = w2; q0.u[3] = w3;
  q1.u[0] = w4; q1.u[1] = w5; q1.u[2] = w6; q1.u[3] = w7;
  p0 = q0.v; p1 = q1.v;
}

#define MFMA32(a, b, c) __builtin_amdgcn_mfma_f32_32x32x16_bf16(a, b, c, 0, 0, 0)

// ---------------------------------------------------------------------------
// Kernel 1: fp32 -> bf16 for the 3 weight matrices only (1M elems each)
// ---------------------------------------------------------------------------
__global__ void __launch_bounds__(256) prep_w(
    const float* __restrict__ wq, const float* __restrict__ wk,
    const float* __restrict__ wv, unsigned short* __restrict__ ws) {
  const int i = blockIdx.x * 256 + threadIdx.x;  // 786432 float4 units
  const int which = i >> 18;
  const int off = (i & 262143) << 2;
  const float* src = which == 0 ? wq : (which == 1 ? wk : wv);
  unsigned short* dst = ws + WS_WQ + (unsigned)which * 1048576u;
  float4 f = *(const float4*)(src + off);
  u32x2 p;
  p.x = pk2(f.x, f.y);
  p.y = pk2(f.z, f.w);
  *(u32x2*)(dst + off) = p;
}

// ---------------------------------------------------------------------------
// Kernel 2: bf16 GEMM  C[4096,1024] = relu(X @ W^T + b), z selects Q/K/V.
// X read DIRECTLY from fp32 inputs (reg-staged + cvt_pk + swizzled ds_write);
// W via global_load_lds from bf16 ws. z==1 pre-scaled; z==2 -> vt. BK=64.
// ---------------------------------------------------------------------------
__global__ void __launch_bounds__(256) qkv_gemm(
    unsigned short* __restrict__ ws, const float* __restrict__ qin,
    const float* __restrict__ kin, const float* __restrict__ vin,
    const float* __restrict__ bq, const float* __restrict__ bk,
    const float* __restrict__ bv) {
  __shared__ alignas(16) unsigned short lA[128 * 64];
  __shared__ alignas(16) unsigned short lB[128 * 64];
  const int z = blockIdx.z;
  const float* A32 = z == 0 ? qin : (z == 1 ? kin : vin);
  const unsigned short* W = ws + WS_WQ + z * 1048576u;
  const float* bias = z == 0 ? bq : (z == 1 ? bk : bv);
  const int tid = threadIdx.x;
  const int lane = tid & 63;
  const int wid = tid >> 6;
  const int wr = wid >> 1, wc = wid & 1;
  const int lin = blockIdx.y * 8 + blockIdx.x;  // 0..255
  const int nid = (lin & 7) * 32 + (lin >> 3);  // XCD-contiguous bm stripes
  const int bm = nid >> 3, bn = nid & 7;
  const int l15 = lane & 15, l4 = lane >> 4;

  f32x4 acc[4][4];
#pragma unroll
  for (int m = 0; m < 4; ++m)
#pragma unroll
    for (int n = 0; n < 4; ++n) acc[m][n] = {0.f, 0.f, 0.f, 0.f};

  const int srow = tid >> 3;  // 0..31
  const int sch = tid & 7;

  float4 ar[4][2];
#define LOADA(kt_)                                                             \
  {                                                                            \
    _Pragma("unroll") for (int rr = 0; rr < 4; ++rr) {                         \
      const int row = rr * 32 + srow;                                          \
      const float* s_ = A32 + (size_t)(bm * 128 + row) * 1024 + (kt_) +        \
                        sch * 8;                                               \
      ar[rr][0] = *(const float4*)(s_);                                        \
      ar[rr][1] = *(const float4*)(s_ + 4);                                    \
    }                                                                          \
  }
#define WRITEA()                                                               \
  {                                                                            \
    _Pragma("unroll") for (int rr = 0; rr < 4; ++rr) {                         \
      const int row = rr * 32 + srow;                                          \
      union { unsigned int u[4]; short8_t v; } t_;                             \
      t_.u[0] = pk2(ar[rr][0].x, ar[rr][0].y);                                 \
      t_.u[1] = pk2(ar[rr][0].z, ar[rr][0].w);                                 \
      t_.u[2] = pk2(ar[rr][1].x, ar[rr][1].y);                                 \
      t_.u[3] = pk2(ar[rr][1].z, ar[rr][1].w);                                 \
      *(short8_t*)((char*)lA + row * 128 + (((sch ^ (row & 7))) * 16)) = t_.v; \
    }                                                                          \
  }

  LOADA(0);
  for (int kt = 0; kt < 1024; kt += 64) {
    __syncthreads();
    WRITEA();
#pragma unroll
    for (int r = 0; r < 4; ++r) {
      const int row = r * 32 + srow;
      const int ch = sch ^ (row & 7);
      gll16(W + (size_t)(bn * 128 + row) * 1024 + kt + ch * 8,
            (char*)lB + r * 4096 + wid * 1024);
    }
    __syncthreads();
    if (kt + 64 < 1024) LOADA(kt + 64);
    short8_t af[4][2], bf[4][2];
#pragma unroll
    for (int m = 0; m < 4; ++m) {
      const int row = wr * 64 + m * 16 + l15;
#pragma unroll
      for (int kk = 0; kk < 2; ++kk)
        af[m][kk] = *(const short8_t*)(
            (const char*)lA + row * 128 + (((kk * 4 + l4) ^ (row & 7)) * 16));
    }
#pragma unroll
    for (int n = 0; n < 4; ++n) {
      const int row = wc * 64 + n * 16 + l15;
#pragma unroll
      for (int kk = 0; kk < 2; ++kk)
        bf[n][kk] = *(const short8_t*)(
            (const char*)lB + row * 128 + (((kk * 4 + l4) ^ (row & 7)) * 16));
    }
#pragma unroll
    for (int m = 0; m < 4; ++m)
#pragma unroll
      for (int n = 0; n < 4; ++n)
#pragma unroll
        for (int kk = 0; kk < 2; ++kk)
          acc[m][n] = __builtin_amdgcn_mfma_f32_16x16x32_bf16(
              af[m][kk], bf[n][kk], acc[m][n], 0, 0, 0);
  }
#undef LOADA
#undef WRITEA

  const int row0 = bm * 128 + wr * 64;
  const int col0 = bn * 128 + wc * 64;
  if (z < 2) {
    const float scl = (z == 1) ? 0.18033688011112042f : 1.0f;  // (1/8)*log2e
    unsigned short* o = ws + WS_QO + z * 4194304u;
#pragma unroll
    for (int n = 0; n < 4; ++n) {
      const int col = col0 + n * 16 + l15;
      const float bb = bias[col];
#pragma unroll
      for (int m = 0; m < 4; ++m)
#pragma unroll
        for (int j = 0; j < 4; ++j) {
          const int row = row0 + m * 16 + l4 * 4 + j;
          o[(size_t)row * 1024 + col] = f2bf(fmaxf(acc[m][n][j] + bb, 0.f) * scl);
        }
    }
  } else {
    unsigned short* vt = ws + WS_VT;
#pragma unroll
    for (int n = 0; n < 4; ++n) {
      const int col = col0 + n * 16 + l15;
      const float bb = bias[col];
      const int nh = col >> 6, d = col & 63;
#pragma unroll
      for (int m = 0; m < 4; ++m) {
        const int t0 = row0 + m * 16 + l4 * 4;
        u32x2 p;
        p.x = f2bf(fmaxf(acc[m][n][0] + bb, 0.f)) |
              ((unsigned int)f2bf(fmaxf(acc[m][n][1] + bb, 0.f)) << 16);
        p.y = f2bf(fmaxf(acc[m][n][2] + bb, 0.f)) |
              ((unsigned int)f2bf(fmaxf(acc[m][n][3] + bb, 0.f)) << 16);
        *(u32x2*)(vt + (size_t)nh * 262144 + (size_t)d * 4096 + t0) = p;
      }
    }
  }
}

// ---------------------------------------------------------------------------
// Kernel 3: flash attention partial, KV-split. Block = (256 q, head, kvh):
// covers t in [kvh*2048, +2048). 8 waves = (qg 0..3) x (tw 0..1); wave =
// 64 q (2 cols share K/V frag reads) x 32 t. KVBLK=64, 32 tiles/block,
// 2-buffer LDS. Writes unnormalized bf16 O-partial [kvh][nh][d][q] +
// f32 row-sums (tw halves combined in LDS first — R13 bugfix).
// ---------------------------------------------------------------------------
__global__ void __launch_bounds__(512, 4) attn_fwd(
    unsigned short* __restrict__ ws) {
  // main: ring buf b: K [64][64]bf16 at b*16384, V at +8192  (32 KB)
  // epilogue overlay: fO[2][64][65] f32 = 33280 B; fRsL[2][256] at +33280
  __shared__ alignas(16) char smem[35328];
  float* fO = (float*)smem;
  float* fRsL = (float*)(smem + 33280);

  const unsigned short* qo = ws + WS_QO;
  const char* koB = (const char*)(ws + WS_KO);
  const char* vtB = (const char*)(ws + WS_VT);
  unsigned short* op = ws;                   // [2][16][64][4096] bf16
  float* rsg = (float*)(ws + 8388608u);      // [2][16][4096] f32
  const int nh = blockIdx.y;
  const int kvh = blockIdx.z;
  const int qb0 = blockIdx.x * 256;
  const int tid = threadIdx.x, lane = tid & 63, wid = tid >> 6;  // wid 0..7
  const int l31 = lane & 31, l5 = lane >> 5;
  const int qg = wid >> 1, tw = wid & 1;

  // staging: 512 threads x one 16B chunk for K and V (64 rows x 8 chunks)
  const int stt = tid >> 3;   // 0..63 row (t for K, d for V)
  const int sch = tid & 7;    // chunk slot
  const unsigned kgoff =
      (unsigned)(stt * 1024 + nh * 64 + ((sch ^ (stt & 7)) * 8)) * 2u +
      (unsigned)kvh * 4194304u;
  const unsigned vgoff =
      (unsigned)(nh * 262144 + stt * 4096 + ((sch ^ (stt & 7)) * 8)) * 2u +
      (unsigned)kvh * 4096u;
  const unsigned ldst = (unsigned)tid * 16u;

  // Q fragments (B-operand: col s, k=d), 2 cols x 4 d-chunks
  short8_t qf[2][4];
#pragma unroll
  for (int c = 0; c < 2; ++c)
#pragma unroll
    for (int kcd = 0; kcd < 4; ++kcd)
      qf[c][kcd] = *(const short8_t*)(
          qo + (size_t)(qb0 + qg * 64 + c * 32 + l31) * 1024 + nh * 64 +
          kcd * 16 + l5 * 8);

  // hoisted LDS read offsets
  int kofl[4];
  {
    const int row = tw * 32 + l31;
#pragma unroll
    for (int kcd = 0; kcd < 4; ++kcd)
      kofl[kcd] = row * 128 + (((kcd * 2 + l5) ^ (row & 7)) * 16);
  }
  int vofl[2][2];
#pragma unroll
  for (int n = 0; n < 2; ++n) {
    const int row = n * 32 + l31;
#pragma unroll
    for (int kc = 0; kc < 2; ++kc)
      vofl[n][kc] = row * 128 + (((tw * 4 + kc * 2 + l5) ^ (row & 7)) * 16);
  }

  f32x16 zro;
#pragma unroll
  for (int r = 0; r < 16; ++r) zro[r] = 0.f;
  f32x16 aco00 = zro, aco01 = zro, aco10 = zro, aco11 = zro;  // [c][n]
  float rsa0 = 0.f, rsa1 = 0.f, rsa2 = 0.f, rsa3 = 0.f;       // col 0 chains
  float rsb0 = 0.f, rsb1 = 0.f, rsb2 = 0.f, rsb3 = 0.f;       // col 1 chains

#define STAGE(buf, ti)                                                         \
  {                                                                            \
    gll16(koB + (kgoff + (unsigned)(ti) * 131072u),                            \
          smem + (buf) * 16384 + ldst);                                        \
    gll16(vtB + (vgoff + (unsigned)(ti) * 128u),                               \
          smem + (buf) * 16384 + 8192 + ldst);                                 \
  }

  STAGE(0, 0);
  __syncthreads();
  int cur = 0;

  for (int i = 0; i < 32; ++i) {
    if (i + 1 < 32) STAGE(cur ^ 1, i + 1);
    const char* sK = smem + cur * 16384;
    const char* sV = sK + 8192;

    // K fragments (shared by both q-cols)
    short8_t kfr[4];
#pragma unroll
    for (int kcd = 0; kcd < 4; ++kcd)
      kfr[kcd] = *(const short8_t*)(sK + kofl[kcd]);

    // S^T = K . Q^T  (K pre-scaled by (1/8)*log2e)
    __builtin_amdgcn_s_setprio(1);
    f32x16 acs0 = MFMA32(kfr[0], qf[0][0], zro);
    f32x16 acs1 = MFMA32(kfr[0], qf[1][0], zro);
#pragma unroll
    for (int kcd = 1; kcd < 4; ++kcd) {
      acs0 = MFMA32(kfr[kcd], qf[0][kcd], acs0);
      acs1 = MFMA32(kfr[kcd], qf[1][kcd], acs1);
    }
    __builtin_amdgcn_s_setprio(0);

    // P = exp2(S); row-sums in 4 chains per col
#pragma unroll
    for (int r = 0; r < 16; r += 4) {
      const float a0 = fexp2(acs0[r]),     a1 = fexp2(acs0[r + 1]);
      const float a2 = fexp2(acs0[r + 2]), a3 = fexp2(acs0[r + 3]);
      acs0[r] = a0; acs0[r + 1] = a1; acs0[r + 2] = a2; acs0[r + 3] = a3;
      rsa0 += a0; rsa1 += a1; rsa2 += a2; rsa3 += a3;
      const float b0 = fexp2(acs1[r]),     b1 = fexp2(acs1[r + 1]);
      const float b2 = fexp2(acs1[r + 2]), b3 = fexp2(acs1[r + 3]);
      acs1[r] = b0; acs1[r + 1] = b1; acs1[r + 2] = b2; acs1[r + 3] = b3;
      rsb0 += b0; rsb1 += b1; rsb2 += b2; rsb3 += b3;
    }

    short8_t pa00, pa01, pa10, pa11;  // [col][k-chunk]
    packP(acs0, pa00, pa01);
    packP(acs1, pa10, pa11);

    // V fragments (shared by both q-cols)
    const short8_t vf00 = *(const short8_t*)(sV + vofl[0][0]);
    const short8_t vf10 = *(const short8_t*)(sV + vofl[1][0]);
    const short8_t vf01 = *(const short8_t*)(sV + vofl[0][1]);
    const short8_t vf11 = *(const short8_t*)(sV + vofl[1][1]);

    // PV
    __builtin_amdgcn_s_setprio(1);
    aco00 = MFMA32(pa00, vf00, aco00);
    aco10 = MFMA32(pa10, vf00, aco10);
    aco01 = MFMA32(pa00, vf10, aco01);
    aco11 = MFMA32(pa10, vf10, aco11);
    aco00 = MFMA32(pa01, vf01, aco00);
    aco10 = MFMA32(pa11, vf01, aco10);
    aco01 = MFMA32(pa01, vf11, aco01);
    aco11 = MFMA32(pa11, vf11, aco11);
    __builtin_amdgcn_s_setprio(0);

    __syncthreads();
    cur ^= 1;
  }
#undef STAGE

  // finish row-sums: chains + cross-t-half (l5) -> per-tw LDS table ->
  // combine tw halves -> ONE global write (R13 bugfix: tw raced before)
  float rsA = (rsa0 + rsa1) + (rsa2 + rsa3);
  float rsB = (rsb0 + rsb1) + (rsb2 + rsb3);
  rsA += __shfl_xor(rsA, 32);
  rsB += __shfl_xor(rsB, 32);
  if (l5 == 0) {
    fRsL[tw * 256 + qg * 64 + l31] = rsA;
    fRsL[tw * 256 + qg * 64 + 32 + l31] = rsB;
  }
  __syncthreads();
  if (tid < 256)
    rsg[(kvh * 16 + nh) * 4096 + qb0 + tid] = fRsL[tid] + fRsL[256 + tid];

  // 4-pass epilogue over q-groups: transpose via padded LDS, combine tw
  // halves, write bf16 O-partial [kvh][nh][d][q] (q-contiguous, coalesced).
  const unsigned onb = (unsigned)(kvh * 16 + nh) * 262144u;
#pragma unroll 1
  for (int p = 0; p < 4; ++p) {
    if (qg == p) {
      float* myO = fO + tw * 4160;  // 64*65
#pragma unroll
      for (int r = 0; r < 16; ++r) {
        const int sl = (r & 3) + 8 * (r >> 2) + 4 * l5;
        myO[l31 * 65 + sl] = aco00[r];
        myO[(l31 + 32) * 65 + sl] = aco01[r];
        myO[l31 * 65 + 32 + sl] = aco10[r];
        myO[(l31 + 32) * 65 + 32 + sl] = aco11[r];
      }
    }
    __syncthreads();
    {
      const int s = tid & 63;
      const int dg = tid >> 6;  // 0..7
      const unsigned ob = onb + (unsigned)(qb0 + p * 64 + s);
#pragma unroll
      for (int j = 0; j < 8; ++j) {
        const int d = dg * 8 + j;
        const float v = fO[d * 65 + s] + fO[4160 + d * 65 + s];
        op[ob + (unsigned)d * 4096u] = f2bf(v);
      }
    }
    __syncthreads();
  }
}

// ---------------------------------------------------------------------------
// Kernel 4: combine kv-halves, normalize, scramble, add residual.
// 1,048,576 float4 quads total -> 4096 blocks x 256 threads.
// out[(nh*256 + d*4 + srow)*1024 + scol] with q = srow*1024 + scol.
// ---------------------------------------------------------------------------
__global__ void __launch_bounds__(256) attn_norm(
    const unsigned short* __restrict__ ws, const float* __restrict__ qin,
    float* __restrict__ out) {
  const int e = blockIdx.x * 256 + threadIdx.x;  // 0 .. 1048575
  const int qq = e & 1023;
  const int nd = e >> 10;         // nh*64 + d, 0..1023
  const int nh = nd >> 6, d = nd & 63;
  const int q0 = qq * 4;
  const unsigned short* op = ws;
  const float* rsg = (const float*)(ws + 8388608u);
  const unsigned ob = (unsigned)nd * 4096u + (unsigned)q0;
  const u32x2 a = *(const u32x2*)(op + ob);
  const u32x2 b = *(const u32x2*)(op + 4194304u + ob);
  const float4 r0 = *(const float4*)(rsg + nh * 4096 + q0);
  const float4 r1 = *(const float4*)(rsg + 65536 + nh * 4096 + q0);
  const int srow = q0 >> 10, scol = q0 & 1023;
  const int idx = (nh * 256 + d * 4 + srow) * 1024 + scol;
  const float4 qv = *(const float4*)(qin + idx);
  float4 o;
  o.x = (b2f((unsigned short)(a.x & 0xffff)) +
         b2f((unsigned short)(b.x & 0xffff))) / (r0.x + r1.x) + qv.x;
  o.y = (b2f((unsigned short)(a.x >> 16)) +
         b2f((unsigned short)(b.x >> 16))) / (r0.y + r1.y) + qv.y;
  o.z = (b2f((unsigned short)(a.y & 0xffff)) +
         b2f((unsigned short)(b.y & 0xffff))) / (r0.z + r1.z) + qv.z;
  o.w = (b2f((unsigned short)(a.y >> 16)) +
         b2f((unsigned short)(b.y >> 16))) / (r0.w + r1.w) + qv.w;
  *(float4*)(out + idx) = o;
}

// ---------------------------------------------------------------------------
extern "C" void kernel_launch(void* const* d_in, const int* in_sizes, int n_in,
                              void* d_out, int out_size, void* d_ws,
                              size_t ws_size, hipStream_t stream) {
  const float* qin = (const float*)d_in[0];
  const float* kin = (const float*)d_in[1];
  const float* vin = (const float*)d_in[2];
  const float* wq = (const float*)d_in[3];
  const float* bq = (const float*)d_in[4];
  const float* wk = (const float*)d_in[5];
  const float* bk = (const float*)d_in[6];
  const float* wv = (const float*)d_in[7];
  const float* bv = (const float*)d_in[8];
  unsigned short* ws = (unsigned short*)d_ws;
  float* out = (float*)d_out;

  prep_w<<<dim3(3072), dim3(256), 0, stream>>>(wq, wk, wv, ws);
  qkv_gemm<<<dim3(8, 32, 3), dim3(256), 0, stream>>>(ws, qin, kin, vin,
                                                     bq, bk, bv);
  attn_fwd<<<dim3(16, 16, 2), dim3(512), 0, stream>>>(ws);
  attn_norm<<<dim3(4096), dim3(256), 0, stream>>>(ws, qin, out);
}

// Round 15
// 130.737 us; speedup vs baseline: 1.9397x; 1.9397x over previous
//
#include <hip/hip_runtime.h>
#include <stdint.h>

// ---------------------------------------------------------------------------
// MultiHeadAttention: B=1, S=4096, H=1024, NH=16, DH=64
//   q = relu(Q @ Wq^T + bq), k = ..., v = ...
//   per head: softmax(q k^T / 8) v,   output scrambled (torch-faithful
//   transpose(0,1,3,2).reshape) + queries.
// R15: revert to R11 (best verified, 131.0 us). R14's KV-split partials
//      round-trip thrashed L2 (FETCH 78->588 MB, attn 80->194 us) — dead end.
//      prep_w (weights only) + fused-A qkv_gemm + single-pass attn (80.4 us).
// ---------------------------------------------------------------------------

#define SEQ 4096
#define HID 1024
#define NHEAD 16
#define DHEAD 64

typedef __attribute__((ext_vector_type(8))) short short8_t;     // 8 x bf16
typedef __attribute__((ext_vector_type(4))) float f32x4;        // 16x16 acc
typedef __attribute__((ext_vector_type(16))) float f32x16;      // 32x32 acc
typedef __attribute__((ext_vector_type(2))) unsigned int u32x2;

// ws layout (bf16 elements) — offsets kept from prior rounds
#define WS_WQ   12582912u   // weights bf16 [1024][1024] x3
#define WS_QO   15728640u   // q proj [4096][1024]
#define WS_KO   19922944u   // k proj (pre-scaled by (1/8)*log2e) [4096][1024]
#define WS_VT   24117248u   // v proj transposed [16][64][4096]

__device__ __forceinline__ unsigned short f2bf(float f) {
  union { float f; unsigned int u; } x; x.f = f;
  unsigned int u = x.u;
  return (unsigned short)((u + 0x7FFFu + ((u >> 16) & 1u)) >> 16);
}

// raw v_exp_f32 — valid: inputs are >= 0 (ReLU'd Q,K dot) and < ~16
__device__ __forceinline__ float fexp2(float x) {
#if __has_builtin(__builtin_amdgcn_exp2f)
  return __builtin_amdgcn_exp2f(x);
#else
  float r; asm("v_exp_f32 %0, %1" : "=v"(r) : "v"(x)); return r;
#endif
}

// packed f32x2 -> bf16x2 (lo = a, hi = b)
__device__ __forceinline__ unsigned int pk2(float a, float b) {
  unsigned int r;
  asm("v_cvt_pk_bf16_f32 %0, %1, %2" : "=v"(r) : "v"(a), "v"(b));
  return r;
}

// swap hi-32-lanes of a with lo-32-lanes of b
__device__ __forceinline__ void pl32swap(unsigned int& a, unsigned int& b) {
  asm("v_permlane32_swap_b32 %0, %1" : "+v"(a), "+v"(b));
}

__device__ __forceinline__ void gll16(const void* g, void* l) {
  __builtin_amdgcn_global_load_lds(
      (const __attribute__((address_space(1))) void*)g,
      (__attribute__((address_space(3))) void*)l, 16, 0, 0);
}

// P pack+redistribute: acs (S^T regs=t, lane=s col) -> two PV A-frags
__device__ __forceinline__ void packP(const f32x16& a, short8_t& p0,
                                      short8_t& p1) {
  unsigned int w0 = pk2(a[0], a[1]),   w1 = pk2(a[2], a[3]);
  unsigned int w2 = pk2(a[4], a[5]),   w3 = pk2(a[6], a[7]);
  unsigned int w4 = pk2(a[8], a[9]),   w5 = pk2(a[10], a[11]);
  unsigned int w6 = pk2(a[12], a[13]), w7 = pk2(a[14], a[15]);
  pl32swap(w0, w2);
  pl32swap(w1, w3);
  pl32swap(w4, w6);
  pl32swap(w5, w7);
  union { unsigned int u[4]; short8_t v; } q0, q1;
  q0.u[0] = w0; q0.u[1] = w1; q0.u[2] = w2; q0.u[3] = w3;
  q1.u[0] = w4; q1.u[1] = w5; q1.u[2] = w6; q1.u[3] = w7;
  p0 = q0.v; p1 = q1.v;
}

#define MFMA32(a, b, c) __builtin_amdgcn_mfma_f32_32x32x16_bf16(a, b, c, 0, 0, 0)

// ---------------------------------------------------------------------------
// Kernel 1: fp32 -> bf16 for the 3 weight matrices only (1M elems each)
// ---------------------------------------------------------------------------
__global__ void __launch_bounds__(256) prep_w(
    const float* __restrict__ wq, const float* __restrict__ wk,
    const float* __restrict__ wv, unsigned short* __restrict__ ws) {
  const int i = blockIdx.x * 256 + threadIdx.x;  // 786432 float4 units
  const int which = i >> 18;
  const int off = (i & 262143) << 2;
  const float* src = which == 0 ? wq : (which == 1 ? wk : wv);
  unsigned short* dst = ws + WS_WQ + (unsigned)which * 1048576u;
  float4 f = *(const float4*)(src + off);
  u32x2 p;
  p.x = pk2(f.x, f.y);
  p.y = pk2(f.z, f.w);
  *(u32x2*)(dst + off) = p;
}

// ---------------------------------------------------------------------------
// Kernel 2: bf16 GEMM  C[4096,1024] = relu(X @ W^T + b), z selects Q/K/V.
// X read DIRECTLY from fp32 inputs: reg-staged (dwordx4, natural order) ->
// cvt_pk -> swizzled ds_write_b128. W via global_load_lds from bf16 ws.
// z==1 (K) pre-scaled by (1/8)*log2e; z==2 writes vt[nh][d][t]. BK=64.
// ---------------------------------------------------------------------------
__global__ void __launch_bounds__(256) qkv_gemm(
    unsigned short* __restrict__ ws, const float* __restrict__ qin,
    const float* __restrict__ kin, const float* __restrict__ vin,
    const float* __restrict__ bq, const float* __restrict__ bk,
    const float* __restrict__ bv) {
  __shared__ alignas(16) unsigned short lA[128 * 64];
  __shared__ alignas(16) unsigned short lB[128 * 64];
  const int z = blockIdx.z;
  const float* A32 = z == 0 ? qin : (z == 1 ? kin : vin);
  const unsigned short* W = ws + WS_WQ + z * 1048576u;
  const float* bias = z == 0 ? bq : (z == 1 ? bk : bv);
  const int tid = threadIdx.x;
  const int lane = tid & 63;
  const int wid = tid >> 6;
  const int wr = wid >> 1, wc = wid & 1;
  const int lin = blockIdx.y * 8 + blockIdx.x;  // 0..255
  const int nid = (lin & 7) * 32 + (lin >> 3);  // XCD-contiguous bm stripes
  const int bm = nid >> 3, bn = nid & 7;
  const int l15 = lane & 15, l4 = lane >> 4;

  f32x4 acc[4][4];
#pragma unroll
  for (int m = 0; m < 4; ++m)
#pragma unroll
    for (int n = 0; n < 4; ++n) acc[m][n] = {0.f, 0.f, 0.f, 0.f};

  // staging coords: 4 rounds x (row = rr*32 + tid>>3, 8-elem chunk = tid&7)
  const int srow = tid >> 3;  // 0..31
  const int sch = tid & 7;

  // A prefetch registers (8 floats x 4 rounds)
  float4 ar[4][2];
#define LOADA(kt_)                                                             \
  {                                                                            \
    _Pragma("unroll") for (int rr = 0; rr < 4; ++rr) {                         \
      const int row = rr * 32 + srow;                                          \
      const float* s_ = A32 + (size_t)(bm * 128 + row) * 1024 + (kt_) +        \
                        sch * 8;                                               \
      ar[rr][0] = *(const float4*)(s_);                                        \
      ar[rr][1] = *(const float4*)(s_ + 4);                                    \
    }                                                                          \
  }
#define WRITEA()                                                               \
  {                                                                            \
    _Pragma("unroll") for (int rr = 0; rr < 4; ++rr) {                         \
      const int row = rr * 32 + srow;                                          \
      union { unsigned int u[4]; short8_t v; } t_;                             \
      t_.u[0] = pk2(ar[rr][0].x, ar[rr][0].y);                                 \
      t_.u[1] = pk2(ar[rr][0].z, ar[rr][0].w);                                 \
      t_.u[2] = pk2(ar[rr][1].x, ar[rr][1].y);                                 \
      t_.u[3] = pk2(ar[rr][1].z, ar[rr][1].w);                                 \
      *(short8_t*)((char*)lA + row * 128 + (((sch ^ (row & 7))) * 16)) = t_.v; \
    }                                                                          \
  }

  LOADA(0);
  for (int kt = 0; kt < 1024; kt += 64) {
    __syncthreads();  // prev compute done; also drains A prefetch loads
    WRITEA();
#pragma unroll
    for (int r = 0; r < 4; ++r) {
      const int row = r * 32 + srow;
      const int ch = sch ^ (row & 7);
      gll16(W + (size_t)(bn * 128 + row) * 1024 + kt + ch * 8,
            (char*)lB + r * 4096 + wid * 1024);
    }
    __syncthreads();  // drains ds_write + gll16
    if (kt + 64 < 1024) LOADA(kt + 64);  // overlaps with compute below
    short8_t af[4][2], bf[4][2];
#pragma unroll
    for (int m = 0; m < 4; ++m) {
      const int row = wr * 64 + m * 16 + l15;
#pragma unroll
      for (int kk = 0; kk < 2; ++kk)
        af[m][kk] = *(const short8_t*)(
            (const char*)lA + row * 128 + (((kk * 4 + l4) ^ (row & 7)) * 16));
    }
#pragma unroll
    for (int n = 0; n < 4; ++n) {
      const int row = wc * 64 + n * 16 + l15;
#pragma unroll
      for (int kk = 0; kk < 2; ++kk)
        bf[n][kk] = *(const short8_t*)(
            (const char*)lB + row * 128 + (((kk * 4 + l4) ^ (row & 7)) * 16));
    }
#pragma unroll
    for (int m = 0; m < 4; ++m)
#pragma unroll
      for (int n = 0; n < 4; ++n)
#pragma unroll
        for (int kk = 0; kk < 2; ++kk)
          acc[m][n] = __builtin_amdgcn_mfma_f32_16x16x32_bf16(
              af[m][kk], bf[n][kk], acc[m][n], 0, 0, 0);
  }
#undef LOADA
#undef WRITEA

  const int row0 = bm * 128 + wr * 64;
  const int col0 = bn * 128 + wc * 64;
  if (z < 2) {
    const float scl = (z == 1) ? 0.18033688011112042f : 1.0f;  // (1/8)*log2e
    unsigned short* o = ws + WS_QO + z * 4194304u;
#pragma unroll
    for (int n = 0; n < 4; ++n) {
      const int col = col0 + n * 16 + l15;
      const float bb = bias[col];
#pragma unroll
      for (int m = 0; m < 4; ++m)
#pragma unroll
        for (int j = 0; j < 4; ++j) {
          const int row = row0 + m * 16 + l4 * 4 + j;
          o[(size_t)row * 1024 + col] = f2bf(fmaxf(acc[m][n][j] + bb, 0.f) * scl);
        }
    }
  } else {
    unsigned short* vt = ws + WS_VT;
#pragma unroll
    for (int n = 0; n < 4; ++n) {
      const int col = col0 + n * 16 + l15;
      const float bb = bias[col];
      const int nh = col >> 6, d = col & 63;
#pragma unroll
      for (int m = 0; m < 4; ++m) {
        const int t0 = row0 + m * 16 + l4 * 4;
        u32x2 p;
        p.x = f2bf(fmaxf(acc[m][n][0] + bb, 0.f)) |
              ((unsigned int)f2bf(fmaxf(acc[m][n][1] + bb, 0.f)) << 16);
        p.y = f2bf(fmaxf(acc[m][n][2] + bb, 0.f)) |
              ((unsigned int)f2bf(fmaxf(acc[m][n][3] + bb, 0.f)) << 16);
        *(u32x2*)(vt + (size_t)nh * 262144 + (size_t)d * 4096 + t0) = p;
      }
    }
  }
}

// ---------------------------------------------------------------------------
// Kernel 3: flash attention (exact R8/R10 structure — best measured, 80.4 us).
// 512-thread blocks; 8 waves = (qg 0..3) x (tw 0..1); wave = 32 q x 32 t.
// KVBLK=64; 2-buffer K/V; S^T = mfma(K, Q^T); raw v_exp_f32; VALU row-sums;
// P in-register (cvt_pk + permlane32_swap). 4-pass transpose epilogue.
// ---------------------------------------------------------------------------
__global__ void __launch_bounds__(512, 4) attn_fwd(
    const unsigned short* __restrict__ ws, const float* __restrict__ qin,
    float* __restrict__ out) {
  // main: lK[2][64*64] 0..16KB, lV[2][64*64] 16..32KB (bf16)
  // epilogue overlay: fO[2][64][33] f32 (16896B) + fRs[2][32] (256B)
  __shared__ alignas(16) char smem[32768];
  const char* lKb = smem;
  const char* lVb = smem + 16384;
  float* fO = (float*)smem;                 // [2][64*33]
  float* fRs = (float*)(smem + 16896);      // [2][32]

  const unsigned short* qo = ws + WS_QO;
  const char* koB = (const char*)(ws + WS_KO);
  const char* vtB = (const char*)(ws + WS_VT);
  const int nh = blockIdx.y;
  const int qb0 = blockIdx.x * 128;
  const int tid = threadIdx.x, lane = tid & 63, wid = tid >> 6;  // wid 0..7
  const int l31 = lane & 31, l5 = lane >> 5;
  const int qg = wid >> 1, tw = wid & 1;
  const int sq = qb0 + qg * 32 + l31;  // this lane's q column

  // staging: 512 threads x one 16B chunk for K and V tiles (64 rows x 8 chunks)
  const int stt = tid >> 3;   // 0..63 row (t for K, d for V)
  const int sch = tid & 7;    // chunk slot
  const unsigned kgoff =
      (unsigned)(stt * 1024 + nh * 64 + ((sch ^ (stt & 7)) * 8)) * 2u;
  const unsigned vgoff =
      (unsigned)(nh * 262144 + stt * 4096 + ((sch ^ (stt & 7)) * 8)) * 2u;
  const unsigned ldst = (unsigned)tid * 16u;

  // Q fragments (B-operand: col s=l31, k=d), 4 d-chunks
  short8_t qf[4];
#pragma unroll
  for (int kcd = 0; kcd < 4; ++kcd)
    qf[kcd] = *(const short8_t*)(qo + (size_t)sq * 1024 + nh * 64 +
                                 kcd * 16 + l5 * 8);

  // hoisted LDS read offsets
  int kofl[4];
  {
    const int row = tw * 32 + l31;
#pragma unroll
    for (int kcd = 0; kcd < 4; ++kcd)
      kofl[kcd] = row * 128 + (((kcd * 2 + l5) ^ (row & 7)) * 16);
  }
  int vofl[2][2];
#pragma unroll
  for (int n = 0; n < 2; ++n) {
    const int row = n * 32 + l31;
#pragma unroll
    for (int kc = 0; kc < 2; ++kc)
      vofl[n][kc] = row * 128 + (((tw * 4 + kc * 2 + l5) ^ (row & 7)) * 16);
  }

  f32x16 zro;
#pragma unroll
  for (int r = 0; r < 16; ++r) zro[r] = 0.f;
  f32x16 aco0 = zro, aco1 = zro;  // O partial [n=d-half]
  float rs0 = 0.f, rs1 = 0.f, rs2 = 0.f, rs3 = 0.f;

#define STAGE(buf, kvb)                                                        \
  {                                                                            \
    gll16(koB + (kgoff + (unsigned)(kvb) * 2048u),                             \
          (char*)lKb + (buf) * 8192 + ldst);                                   \
    gll16(vtB + (vgoff + (unsigned)(kvb) * 2u),                                \
          (char*)lVb + (buf) * 8192 + ldst);                                   \
  }

  STAGE(0, 0);
  __syncthreads();
  int cur = 0;

  for (int kv = 0; kv < 4096; kv += 64) {
    if (kv + 64 < 4096) STAGE(cur ^ 1, kv + 64);
    const char* lKc = lKb + cur * 8192;
    const char* lVc = lVb + cur * 8192;

    // S^T[t][s] = sum_d K[t][d] Q[s][d]  (K pre-scaled by (1/8)*log2e)
    __builtin_amdgcn_s_setprio(1);
    f32x16 acs = MFMA32(*(const short8_t*)(lKc + kofl[0]), qf[0], zro);
#pragma unroll
    for (int kcd = 1; kcd < 4; ++kcd)
      acs = MFMA32(*(const short8_t*)(lKc + kofl[kcd]), qf[kcd], acs);
    __builtin_amdgcn_s_setprio(0);

    // P = exp2(S); row-sums in 4 chains
#pragma unroll
    for (int r = 0; r < 16; r += 4) {
      const float p0 = fexp2(acs[r]);
      const float p1 = fexp2(acs[r + 1]);
      const float p2 = fexp2(acs[r + 2]);
      const float p3 = fexp2(acs[r + 3]);
      acs[r] = p0; acs[r + 1] = p1; acs[r + 2] = p2; acs[r + 3] = p3;
      rs0 += p0; rs1 += p1; rs2 += p2; rs3 += p3;
    }

    short8_t pa0, pa1;
    packP(acs, pa0, pa1);

    // PV: O[s][d] += sum_t P[s][t] V[t][d]
    const short8_t vf00 = *(const short8_t*)(lVc + vofl[0][0]);
    const short8_t vf10 = *(const short8_t*)(lVc + vofl[1][0]);
    const short8_t vf01 = *(const short8_t*)(lVc + vofl[0][1]);
    const short8_t vf11 = *(const short8_t*)(lVc + vofl[1][1]);
    __builtin_amdgcn_s_setprio(1);
    aco0 = MFMA32(pa0, vf00, aco0);
    aco1 = MFMA32(pa0, vf10, aco1);
    aco0 = MFMA32(pa1, vf01, aco0);
    aco1 = MFMA32(pa1, vf11, aco1);
    __builtin_amdgcn_s_setprio(0);

    __syncthreads();
    cur ^= 1;
  }

  // complete row-sum: chains + cross-t-half (l5)
  float rs = (rs0 + rs1) + (rs2 + rs3);
  rs += __shfl_xor(rs, 32);

  // 4-pass epilogue over q-groups: transpose via padded LDS overlay,
  // combine tw halves, normalize, scramble, add residual.
#pragma unroll 1
  for (int p = 0; p < 4; ++p) {
    if (qg == p) {
      float* myO = fO + tw * 2112;  // 64*33
#pragma unroll
      for (int r = 0; r < 16; ++r) {
        const int sl = (r & 3) + 8 * (r >> 2) + 4 * l5;
        myO[l31 * 33 + sl] = aco0[r];
        myO[(l31 + 32) * 33 + sl] = aco1[r];
      }
      if (l5 == 0) fRs[tw * 32 + l31] = rs;
    }
    __syncthreads();
    {
      const int s = tid & 31;
      const int dg = tid >> 5;  // 0..15
      const int sg = qb0 + p * 32 + s;
      const float inv = 1.f / (fRs[s] + fRs[32 + s]);
      const int scol = sg & 1023, srow = sg >> 10;
#pragma unroll
      for (int i = 0; i < 4; ++i) {
        const int d = dg * 4 + i;
        const float v = fO[d * 33 + s] + fO[2112 + d * 33 + s];
        const int idx = (nh * 256 + d * 4 + srow) * 1024 + scol;
        out[idx] = qin[idx] + v * inv;
      }
    }
    __syncthreads();
  }
#undef STAGE
}

// ---------------------------------------------------------------------------
extern "C" void kernel_launch(void* const* d_in, const int* in_sizes, int n_in,
                              void* d_out, int out_size, void* d_ws,
                              size_t ws_size, hipStream_t stream) {
  const float* qin = (const float*)d_in[0];
  const float* kin = (const float*)d_in[1];
  const float* vin = (const float*)d_in[2];
  const float* wq = (const float*)d_in[3];
  const float* bq = (const float*)d_in[4];
  const float* wk = (const float*)d_in[5];
  const float* bk = (const float*)d_in[6];
  const float* wv = (const float*)d_in[7];
  const float* bv = (const float*)d_in[8];
  unsigned short* ws = (unsigned short*)d_ws;
  float* out = (float*)d_out;

  prep_w<<<dim3(3072), dim3(256), 0, stream>>>(wq, wk, wv, ws);
  qkv_gemm<<<dim3(8, 32, 3), dim3(256), 0, stream>>>(ws, qin, kin, vin,
                                                     bq, bk, bv);
  attn_fwd<<<dim3(32, 16), dim3(512), 0, stream>>>(ws, qin, out);
}

// Round 16
// 129.384 us; speedup vs baseline: 1.9600x; 1.0105x over previous
//
#include <hip/hip_runtime.h>
#include <stdint.h>

// ---------------------------------------------------------------------------
// MultiHeadAttention: B=1, S=4096, H=1024, NH=16, DH=64
//   q = relu(Q @ Wq^T + bq), k = ..., v = ...
//   per head: softmax(q k^T / 8) v,   output scrambled (torch-faithful
//   transpose(0,1,3,2).reshape) + queries.
// R16: R15 + attn row-sums via ones-column MFMA (R5-verified pattern) —
//      deletes 16 dependent VALU adds/tile + end shuffles; acl costs 16
//      AGPRs (96->112 unified, still under the 4-wave 128 cap).
//      prep_w / qkv_gemm unchanged from R11/R15.
// ---------------------------------------------------------------------------

#define SEQ 4096
#define HID 1024
#define NHEAD 16
#define DHEAD 64

typedef __attribute__((ext_vector_type(8))) short short8_t;     // 8 x bf16
typedef __attribute__((ext_vector_type(4))) float f32x4;        // 16x16 acc
typedef __attribute__((ext_vector_type(16))) float f32x16;      // 32x32 acc
typedef __attribute__((ext_vector_type(2))) unsigned int u32x2;

// ws layout (bf16 elements) — offsets kept from prior rounds
#define WS_WQ   12582912u   // weights bf16 [1024][1024] x3
#define WS_QO   15728640u   // q proj [4096][1024]
#define WS_KO   19922944u   // k proj (pre-scaled by (1/8)*log2e) [4096][1024]
#define WS_VT   24117248u   // v proj transposed [16][64][4096]

__device__ __forceinline__ unsigned short f2bf(float f) {
  union { float f; unsigned int u; } x; x.f = f;
  unsigned int u = x.u;
  return (unsigned short)((u + 0x7FFFu + ((u >> 16) & 1u)) >> 16);
}

// raw v_exp_f32 — valid: inputs are >= 0 (ReLU'd Q,K dot) and < ~16
__device__ __forceinline__ float fexp2(float x) {
#if __has_builtin(__builtin_amdgcn_exp2f)
  return __builtin_amdgcn_exp2f(x);
#else
  float r; asm("v_exp_f32 %0, %1" : "=v"(r) : "v"(x)); return r;
#endif
}

// packed f32x2 -> bf16x2 (lo = a, hi = b)
__device__ __forceinline__ unsigned int pk2(float a, float b) {
  unsigned int r;
  asm("v_cvt_pk_bf16_f32 %0, %1, %2" : "=v"(r) : "v"(a), "v"(b));
  return r;
}

// swap hi-32-lanes of a with lo-32-lanes of b
__device__ __forceinline__ void pl32swap(unsigned int& a, unsigned int& b) {
  asm("v_permlane32_swap_b32 %0, %1" : "+v"(a), "+v"(b));
}

__device__ __forceinline__ void gll16(const void* g, void* l) {
  __builtin_amdgcn_global_load_lds(
      (const __attribute__((address_space(1))) void*)g,
      (__attribute__((address_space(3))) void*)l, 16, 0, 0);
}

// P pack+redistribute: acs (S^T regs=t, lane=s col) -> two PV A-frags
__device__ __forceinline__ void packP(const f32x16& a, short8_t& p0,
                                      short8_t& p1) {
  unsigned int w0 = pk2(a[0], a[1]),   w1 = pk2(a[2], a[3]);
  unsigned int w2 = pk2(a[4], a[5]),   w3 = pk2(a[6], a[7]);
  unsigned int w4 = pk2(a[8], a[9]),   w5 = pk2(a[10], a[11]);
  unsigned int w6 = pk2(a[12], a[13]), w7 = pk2(a[14], a[15]);
  pl32swap(w0, w2);
  pl32swap(w1, w3);
  pl32swap(w4, w6);
  pl32swap(w5, w7);
  union { unsigned int u[4]; short8_t v; } q0, q1;
  q0.u[0] = w0; q0.u[1] = w1; q0.u[2] = w2; q0.u[3] = w3;
  q1.u[0] = w4; q1.u[1] = w5; q1.u[2] = w6; q1.u[3] = w7;
  p0 = q0.v; p1 = q1.v;
}

#define MFMA32(a, b, c) __builtin_amdgcn_mfma_f32_32x32x16_bf16(a, b, c, 0, 0, 0)

// ---------------------------------------------------------------------------
// Kernel 1: fp32 -> bf16 for the 3 weight matrices only (1M elems each)
// ---------------------------------------------------------------------------
__global__ void __launch_bounds__(256) prep_w(
    const float* __restrict__ wq, const float* __restrict__ wk,
    const float* __restrict__ wv, unsigned short* __restrict__ ws) {
  const int i = blockIdx.x * 256 + threadIdx.x;  // 786432 float4 units
  const int which = i >> 18;
  const int off = (i & 262143) << 2;
  const float* src = which == 0 ? wq : (which == 1 ? wk : wv);
  unsigned short* dst = ws + WS_WQ + (unsigned)which * 1048576u;
  float4 f = *(const float4*)(src + off);
  u32x2 p;
  p.x = pk2(f.x, f.y);
  p.y = pk2(f.z, f.w);
  *(u32x2*)(dst + off) = p;
}

// ---------------------------------------------------------------------------
// Kernel 2: bf16 GEMM  C[4096,1024] = relu(X @ W^T + b), z selects Q/K/V.
// X read DIRECTLY from fp32 inputs: reg-staged (dwordx4, natural order) ->
// cvt_pk -> swizzled ds_write_b128. W via global_load_lds from bf16 ws.
// z==1 (K) pre-scaled by (1/8)*log2e; z==2 writes vt[nh][d][t]. BK=64.
// ---------------------------------------------------------------------------
__global__ void __launch_bounds__(256) qkv_gemm(
    unsigned short* __restrict__ ws, const float* __restrict__ qin,
    const float* __restrict__ kin, const float* __restrict__ vin,
    const float* __restrict__ bq, const float* __restrict__ bk,
    const float* __restrict__ bv) {
  __shared__ alignas(16) unsigned short lA[128 * 64];
  __shared__ alignas(16) unsigned short lB[128 * 64];
  const int z = blockIdx.z;
  const float* A32 = z == 0 ? qin : (z == 1 ? kin : vin);
  const unsigned short* W = ws + WS_WQ + z * 1048576u;
  const float* bias = z == 0 ? bq : (z == 1 ? bk : bv);
  const int tid = threadIdx.x;
  const int lane = tid & 63;
  const int wid = tid >> 6;
  const int wr = wid >> 1, wc = wid & 1;
  const int lin = blockIdx.y * 8 + blockIdx.x;  // 0..255
  const int nid = (lin & 7) * 32 + (lin >> 3);  // XCD-contiguous bm stripes
  const int bm = nid >> 3, bn = nid & 7;
  const int l15 = lane & 15, l4 = lane >> 4;

  f32x4 acc[4][4];
#pragma unroll
  for (int m = 0; m < 4; ++m)
#pragma unroll
    for (int n = 0; n < 4; ++n) acc[m][n] = {0.f, 0.f, 0.f, 0.f};

  // staging coords: 4 rounds x (row = rr*32 + tid>>3, 8-elem chunk = tid&7)
  const int srow = tid >> 3;  // 0..31
  const int sch = tid & 7;

  // A prefetch registers (8 floats x 4 rounds)
  float4 ar[4][2];
#define LOADA(kt_)                                                             \
  {                                                                            \
    _Pragma("unroll") for (int rr = 0; rr < 4; ++rr) {                         \
      const int row = rr * 32 + srow;                                          \
      const float* s_ = A32 + (size_t)(bm * 128 + row) * 1024 + (kt_) +        \
                        sch * 8;                                               \
      ar[rr][0] = *(const float4*)(s_);                                        \
      ar[rr][1] = *(const float4*)(s_ + 4);                                    \
    }                                                                          \
  }
#define WRITEA()                                                               \
  {                                                                            \
    _Pragma("unroll") for (int rr = 0; rr < 4; ++rr) {                         \
      const int row = rr * 32 + srow;                                          \
      union { unsigned int u[4]; short8_t v; } t_;                             \
      t_.u[0] = pk2(ar[rr][0].x, ar[rr][0].y);                                 \
      t_.u[1] = pk2(ar[rr][0].z, ar[rr][0].w);                                 \
      t_.u[2] = pk2(ar[rr][1].x, ar[rr][1].y);                                 \
      t_.u[3] = pk2(ar[rr][1].z, ar[rr][1].w);                                 \
      *(short8_t*)((char*)lA + row * 128 + (((sch ^ (row & 7))) * 16)) = t_.v; \
    }                                                                          \
  }

  LOADA(0);
  for (int kt = 0; kt < 1024; kt += 64) {
    __syncthreads();  // prev compute done; also drains A prefetch loads
    WRITEA();
#pragma unroll
    for (int r = 0; r < 4; ++r) {
      const int row = r * 32 + srow;
      const int ch = sch ^ (row & 7);
      gll16(W + (size_t)(bn * 128 + row) * 1024 + kt + ch * 8,
            (char*)lB + r * 4096 + wid * 1024);
    }
    __syncthreads();  // drains ds_write + gll16
    if (kt + 64 < 1024) LOADA(kt + 64);  // overlaps with compute below
    short8_t af[4][2], bf[4][2];
#pragma unroll
    for (int m = 0; m < 4; ++m) {
      const int row = wr * 64 + m * 16 + l15;
#pragma unroll
      for (int kk = 0; kk < 2; ++kk)
        af[m][kk] = *(const short8_t*)(
            (const char*)lA + row * 128 + (((kk * 4 + l4) ^ (row & 7)) * 16));
    }
#pragma unroll
    for (int n = 0; n < 4; ++n) {
      const int row = wc * 64 + n * 16 + l15;
#pragma unroll
      for (int kk = 0; kk < 2; ++kk)
        bf[n][kk] = *(const short8_t*)(
            (const char*)lB + row * 128 + (((kk * 4 + l4) ^ (row & 7)) * 16));
    }
#pragma unroll
    for (int m = 0; m < 4; ++m)
#pragma unroll
      for (int n = 0; n < 4; ++n)
#pragma unroll
        for (int kk = 0; kk < 2; ++kk)
          acc[m][n] = __builtin_amdgcn_mfma_f32_16x16x32_bf16(
              af[m][kk], bf[n][kk], acc[m][n], 0, 0, 0);
  }
#undef LOADA
#undef WRITEA

  const int row0 = bm * 128 + wr * 64;
  const int col0 = bn * 128 + wc * 64;
  if (z < 2) {
    const float scl = (z == 1) ? 0.18033688011112042f : 1.0f;  // (1/8)*log2e
    unsigned short* o = ws + WS_QO + z * 4194304u;
#pragma unroll
    for (int n = 0; n < 4; ++n) {
      const int col = col0 + n * 16 + l15;
      const float bb = bias[col];
#pragma unroll
      for (int m = 0; m < 4; ++m)
#pragma unroll
        for (int j = 0; j < 4; ++j) {
          const int row = row0 + m * 16 + l4 * 4 + j;
          o[(size_t)row * 1024 + col] = f2bf(fmaxf(acc[m][n][j] + bb, 0.f) * scl);
        }
    }
  } else {
    unsigned short* vt = ws + WS_VT;
#pragma unroll
    for (int n = 0; n < 4; ++n) {
      const int col = col0 + n * 16 + l15;
      const float bb = bias[col];
      const int nh = col >> 6, d = col & 63;
#pragma unroll
      for (int m = 0; m < 4; ++m) {
        const int t0 = row0 + m * 16 + l4 * 4;
        u32x2 p;
        p.x = f2bf(fmaxf(acc[m][n][0] + bb, 0.f)) |
              ((unsigned int)f2bf(fmaxf(acc[m][n][1] + bb, 0.f)) << 16);
        p.y = f2bf(fmaxf(acc[m][n][2] + bb, 0.f)) |
              ((unsigned int)f2bf(fmaxf(acc[m][n][3] + bb, 0.f)) << 16);
        *(u32x2*)(vt + (size_t)nh * 262144 + (size_t)d * 4096 + t0) = p;
      }
    }
  }
}

// ---------------------------------------------------------------------------
// Kernel 3: flash attention (R8/R15 structure + ones-MFMA row-sums).
// 512-thread blocks; 8 waves = (qg 0..3) x (tw 0..1); wave = 32 q x 32 t.
// KVBLK=64; 2-buffer K/V; S^T = mfma(K, Q^T); raw v_exp_f32; row-sums via
// ones-column MFMA into acl (R5-verified); P in-register (cvt_pk +
// permlane32_swap). 4-pass transpose epilogue.
// ---------------------------------------------------------------------------
__global__ void __launch_bounds__(512, 4) attn_fwd(
    const unsigned short* __restrict__ ws, const float* __restrict__ qin,
    float* __restrict__ out) {
  // main: lK[2][64*64] 0..16KB, lV[2][64*64] 16..32KB (bf16)
  // epilogue overlay: fO[2][64][33] f32 (16896B) + fRs[2][32] (256B)
  __shared__ alignas(16) char smem[32768];
  const char* lKb = smem;
  const char* lVb = smem + 16384;
  float* fO = (float*)smem;                 // [2][64*33]
  float* fRs = (float*)(smem + 16896);      // [2][32]

  const unsigned short* qo = ws + WS_QO;
  const char* koB = (const char*)(ws + WS_KO);
  const char* vtB = (const char*)(ws + WS_VT);
  const int nh = blockIdx.y;
  const int qb0 = blockIdx.x * 128;
  const int tid = threadIdx.x, lane = tid & 63, wid = tid >> 6;  // wid 0..7
  const int l31 = lane & 31, l5 = lane >> 5;
  const int qg = wid >> 1, tw = wid & 1;
  const int sq = qb0 + qg * 32 + l31;  // this lane's q column

  // staging: 512 threads x one 16B chunk for K and V tiles (64 rows x 8 chunks)
  const int stt = tid >> 3;   // 0..63 row (t for K, d for V)
  const int sch = tid & 7;    // chunk slot
  const unsigned kgoff =
      (unsigned)(stt * 1024 + nh * 64 + ((sch ^ (stt & 7)) * 8)) * 2u;
  const unsigned vgoff =
      (unsigned)(nh * 262144 + stt * 4096 + ((sch ^ (stt & 7)) * 8)) * 2u;
  const unsigned ldst = (unsigned)tid * 16u;

  // Q fragments (B-operand: col s=l31, k=d), 4 d-chunks
  short8_t qf[4];
#pragma unroll
  for (int kcd = 0; kcd < 4; ++kcd)
    qf[kcd] = *(const short8_t*)(qo + (size_t)sq * 1024 + nh * 64 +
                                 kcd * 16 + l5 * 8);

  // ones B-fragment for row-sum MFMA (col 0 = 1.0 across all k)
  union { unsigned int u[4]; short8_t v; } ou;
  {
    const unsigned int ov = (l31 == 0) ? 0x3F803F80u : 0u;
    ou.u[0] = ov; ou.u[1] = ov; ou.u[2] = ov; ou.u[3] = ov;
  }
  const short8_t ones = ou.v;

  // hoisted LDS read offsets
  int kofl[4];
  {
    const int row = tw * 32 + l31;
#pragma unroll
    for (int kcd = 0; kcd < 4; ++kcd)
      kofl[kcd] = row * 128 + (((kcd * 2 + l5) ^ (row & 7)) * 16);
  }
  int vofl[2][2];
#pragma unroll
  for (int n = 0; n < 2; ++n) {
    const int row = n * 32 + l31;
#pragma unroll
    for (int kc = 0; kc < 2; ++kc)
      vofl[n][kc] = row * 128 + (((tw * 4 + kc * 2 + l5) ^ (row & 7)) * 16);
  }

  f32x16 zro;
#pragma unroll
  for (int r = 0; r < 16; ++r) zro[r] = 0.f;
  f32x16 aco0 = zro, aco1 = zro;  // O partial [n=d-half]
  f32x16 acl = zro;               // row-sums (valid at lanes l31==0)

#define STAGE(buf, kvb)                                                        \
  {                                                                            \
    gll16(koB + (kgoff + (unsigned)(kvb) * 2048u),                             \
          (char*)lKb + (buf) * 8192 + ldst);                                   \
    gll16(vtB + (vgoff + (unsigned)(kvb) * 2u),                                \
          (char*)lVb + (buf) * 8192 + ldst);                                   \
  }

  STAGE(0, 0);
  __syncthreads();
  int cur = 0;

  for (int kv = 0; kv < 4096; kv += 64) {
    if (kv + 64 < 4096) STAGE(cur ^ 1, kv + 64);
    const char* lKc = lKb + cur * 8192;
    const char* lVc = lVb + cur * 8192;

    // S^T[t][s] = sum_d K[t][d] Q[s][d]  (K pre-scaled by (1/8)*log2e)
    __builtin_amdgcn_s_setprio(1);
    f32x16 acs = MFMA32(*(const short8_t*)(lKc + kofl[0]), qf[0], zro);
#pragma unroll
    for (int kcd = 1; kcd < 4; ++kcd)
      acs = MFMA32(*(const short8_t*)(lKc + kofl[kcd]), qf[kcd], acs);
    __builtin_amdgcn_s_setprio(0);

    // P = exp2(S) (raw v_exp_f32; no max subtraction needed)
#pragma unroll
    for (int r = 0; r < 16; ++r) acs[r] = fexp2(acs[r]);

    short8_t pa0, pa1;
    packP(acs, pa0, pa1);

    // PV: O[s][d] += sum_t P[s][t] V[t][d]; row-sums via ones-column MFMA
    const short8_t vf00 = *(const short8_t*)(lVc + vofl[0][0]);
    const short8_t vf10 = *(const short8_t*)(lVc + vofl[1][0]);
    const short8_t vf01 = *(const short8_t*)(lVc + vofl[0][1]);
    const short8_t vf11 = *(const short8_t*)(lVc + vofl[1][1]);
    __builtin_amdgcn_s_setprio(1);
    aco0 = MFMA32(pa0, vf00, aco0);
    aco1 = MFMA32(pa0, vf10, aco1);
    acl = MFMA32(pa0, ones, acl);
    aco0 = MFMA32(pa1, vf01, aco0);
    aco1 = MFMA32(pa1, vf11, aco1);
    acl = MFMA32(pa1, ones, acl);
    __builtin_amdgcn_s_setprio(0);

    __syncthreads();
    cur ^= 1;
  }

  // 4-pass epilogue over q-groups: transpose via padded LDS overlay,
  // combine tw halves, normalize, scramble, add residual.
  // acl[r] at lanes l31==0 holds rowsum for s = (r&3)+8*(r>>2)+4*l5.
#pragma unroll 1
  for (int p = 0; p < 4; ++p) {
    if (qg == p) {
      float* myO = fO + tw * 2112;  // 64*33
#pragma unroll
      for (int r = 0; r < 16; ++r) {
        const int sl = (r & 3) + 8 * (r >> 2) + 4 * l5;
        myO[l31 * 33 + sl] = aco0[r];
        myO[(l31 + 32) * 33 + sl] = aco1[r];
      }
      if (l31 == 0) {
#pragma unroll
        for (int r = 0; r < 16; ++r) {
          const int sl = (r & 3) + 8 * (r >> 2) + 4 * l5;
          fRs[tw * 32 + sl] = acl[r];
        }
      }
    }
    __syncthreads();
    {
      const int s = tid & 31;
      const int dg = tid >> 5;  // 0..15
      const int sg = qb0 + p * 32 + s;
      const float inv = 1.f / (fRs[s] + fRs[32 + s]);
      const int scol = sg & 1023, srow = sg >> 10;
#pragma unroll
      for (int i = 0; i < 4; ++i) {
        const int d = dg * 4 + i;
        const float v = fO[d * 33 + s] + fO[2112 + d * 33 + s];
        const int idx = (nh * 256 + d * 4 + srow) * 1024 + scol;
        out[idx] = qin[idx] + v * inv;
      }
    }
    __syncthreads();
  }
#undef STAGE
}

// ---------------------------------------------------------------------------
extern "C" void kernel_launch(void* const* d_in, const int* in_sizes, int n_in,
                              void* d_out, int out_size, void* d_ws,
                              size_t ws_size, hipStream_t stream) {
  const float* qin = (const float*)d_in[0];
  const float* kin = (const float*)d_in[1];
  const float* vin = (const float*)d_in[2];
  const float* wq = (const float*)d_in[3];
  const float* bq = (const float*)d_in[4];
  const float* wk = (const float*)d_in[5];
  const float* bk = (const float*)d_in[6];
  const float* wv = (const float*)d_in[7];
  const float* bv = (const float*)d_in[8];
  unsigned short* ws = (unsigned short*)d_ws;
  float* out = (float*)d_out;

  prep_w<<<dim3(3072), dim3(256), 0, stream>>>(wq, wk, wv, ws);
  qkv_gemm<<<dim3(8, 32, 3), dim3(256), 0, stream>>>(ws, qin, kin, vin,
                                                     bq, bk, bv);
  attn_fwd<<<dim3(32, 16), dim3(512), 0, stream>>>(ws, qin, out);
}